// Round 10
// baseline (191.970 us; speedup 1.0000x reference)
//
#include <hip/hip_runtime.h>

// VQ quantizer, fp32: z [131072,64], e [2048,64].
// d_out (flat f32): z_q [131072*64] | indices [131072] (floats) | loss [1].
//
// R15 (kept): SINGLE-PRODUCT F16 MFMA scan, 131 -> 96us.
// R16 (kept): EPS_S=0.02 (9.1 sigma), fixup batched RFIX rows/sweep.
// R17: (a) scan K-loop: counted-vmcnt ring (T4), NO __syncthreads in loop.
//      4-slot ring of 4KB pair-slabs; per iter: STAGE(t+2) -> s_waitcnt
//      vmcnt(2) (retires own tile-t quarter; t+1,t+2 stay IN FLIGHT) ->
//      raw s_barrier -> ds_read+MFMA+argmax. R14 verified this discipline
//      correct; its regression was spills from _p staging arrays (FETCH
//      +5MB) which R15's inline-consume COMPUTE doesn't have (VGPR 76).
//      Exactly ONE global_load_lds per iter -> exact vmcnt counting.
//      A-frags built+pinned BEFORE a one-time vmcnt(0) so counting is clean.
//      (b) fixup RFIX 4 -> 8: eT L2 traffic halves again (~218MB).
// Flags CAP 65536 + scan-all fallback. T=0 => z_out = z_q = e[best].

#define N_ROWS 131072
#define ZD 64
#define KCODES 2048
#define RF 4                 // 16-row fragments per wave (64 rows/wave)
#define EPS_S 0.02f          // 9.1 sigma of f16 scan pairwise error
#define FLAG_CAP 65536
#define RFIX 8               // rows per eT sweep in fixup

using f16x8   = __attribute__((ext_vector_type(8))) _Float16;
using floatx4 = __attribute__((ext_vector_type(4))) float;

// ws byte layout:
//       0: loss f32 | 4: flag count u32
//    4096: esn f32[2048]   (= -esq/2, summed in f64)
//   16384: esq64 f64[2048]
//   32768: et16, 128 tiles x 2048B; tile = [kb 0..7][code 0..15][8 k] f16
//          (kb = dim>>3, j = dim&7)   ends 294912
//  294912: flags u32[65536]   (ends 557056)
//  557056: eT f32[64*2048]    (ends 1081344)

__global__ void prep_kernel(const float* __restrict__ e, float* __restrict__ ws) {
    int t = threadIdx.x, lane = t & 63, w = t >> 6;
    if (blockIdx.x == 0 && t == 0) { ws[0] = 0.0f; ((unsigned int*)ws)[1] = 0u; }
    int c = blockIdx.x * 4 + w;                   // 512 blocks x 4 waves = 2048
    float* esn = ws + 1024;
    double* esq64 = (double*)((char*)ws + 16384);
    unsigned short* et = (unsigned short*)((char*)ws + 32768);
    float* eT = (float*)((char*)ws + 557056);

    float x = e[(size_t)c * ZD + lane];           // lane = dim k, coalesced
    union { _Float16 h; unsigned short u; } cv;
    cv.h = (_Float16)x;                           // RTN f32->f16
    // swizzled tile layout: tile = c>>4, 1024 u16 per tile
    int base = ((c >> 4) << 10) + ((lane >> 3) << 7) + ((c & 15) << 3) + (lane & 7);
    et[base] = cv.u;
    eT[lane * KCODES + c] = x;
    double s = (double)x * (double)x;
    for (int off = 1; off < 64; off <<= 1) s += __shfl_xor(s, off, 64);
    if (lane == 0) { esq64[c] = s; esn[c] = (float)(-0.5 * s); }
}

// 8 MFMAs + argmax update for one 16-code tile (single f16 product).
// Top-2 invariant mval >= mv2: new mv2 = median(s, mval_old, mv2).
#define COMPUTE(H0, H1, EN, FCOL) do {                                       \
    floatx4 _ai = {EN, EN, EN, EN};                                          \
    _Pragma("unroll")                                                        \
    for (int _rf = 0; _rf < RF; _rf++) {                                     \
        floatx4 acc;                                                         \
        acc = __builtin_amdgcn_mfma_f32_16x16x32_f16(Fh[_rf][0], H0, _ai, 0, 0, 0); \
        acc = __builtin_amdgcn_mfma_f32_16x16x32_f16(Fh[_rf][1], H1, acc, 0, 0, 0); \
        _Pragma("unroll")                                                    \
        for (int _r = 0; _r < 4; _r++) {                                     \
            float _s  = acc[_r];                                             \
            bool  _gt = _s > mval[_rf][_r];                                  \
            mv2[_rf][_r]  = __builtin_amdgcn_fmed3f(_s, mval[_rf][_r], mv2[_rf][_r]); \
            midx[_rf][_r] = _gt ? (FCOL) : midx[_rf][_r];                    \
            mval[_rf][_r] = fmaxf(_s, mval[_rf][_r]);                        \
        }                                                                    \
    }                                                                        \
} while (0)

// Stage one 4KB PAIR of tiles (2x 2KB) into ring slot BUF: 256 thr x 16B,
// lane*16-linear (ONE global_load_lds per thread -> exact vmcnt counting).
#define STAGEP(BUF, P) do {                                                  \
    const char* _src = etiles + ((size_t)((P) & 63) << 12)                   \
                       + ((size_t)threadIdx.x << 4);                         \
    __builtin_amdgcn_global_load_lds(                                        \
        (const __attribute__((address_space(1))) unsigned int*)_src,         \
        (__attribute__((address_space(3))) unsigned int*)&tilebuf[BUF][w << 10], \
        16, 0, 0);                                                           \
} while (0)

// T4 ring iteration over a tile PAIR (CT = pair idx 0..63, slot = CT&3):
// stage pair CT+2, counted vmcnt (own pair-CT quarter retired; CT+1,CT+2
// stay in flight), raw barrier (composes per-wave guarantees block-wide),
// then ds_read + compute. No full drain anywhere in the loop.
#define ITER_R(CT) do {                                                      \
    STAGEP(((CT) + 2) & 3, (CT) + 2);                                        \
    asm volatile("s_waitcnt vmcnt(2)" ::: "memory");                         \
    __builtin_amdgcn_s_barrier();                                            \
    float _en0 = esn_sm[(CT) * 32 + lrow];                                   \
    float _en1 = esn_sm[(CT) * 32 + 16 + lrow];                              \
    const char* _tb = tilebuf[(CT) & 3];                                     \
    f16x8 h0, h1;                                                            \
    h0 = *(const f16x8*)(const void*)(_tb + (lane << 4));                    \
    h1 = *(const f16x8*)(const void*)(_tb + 1024 + (lane << 4));             \
    COMPUTE(h0, h1, _en0, fcol);                                             \
    fcol += 16.0f;                                                           \
    h0 = *(const f16x8*)(const void*)(_tb + 2048 + (lane << 4));             \
    h1 = *(const f16x8*)(const void*)(_tb + 3072 + (lane << 4));             \
    COMPUTE(h0, h1, _en1, fcol);                                             \
    fcol += 16.0f;                                                           \
} while (0)

__global__ __launch_bounds__(256, 2) void vq_mfma(
        const float* __restrict__ z, const float* __restrict__ e,
        float* __restrict__ ws, float* __restrict__ out) {
    const char* etiles = (const char*)ws + 32768;
    unsigned int* cntp  = (unsigned int*)ws + 1;
    unsigned int* flags = (unsigned int*)((char*)ws + 294912);

    __shared__ __attribute__((aligned(16))) char tilebuf[4][4096];
    __shared__ __attribute__((aligned(16))) float esn_sm[KCODES];

    int lane = threadIdx.x & 63;
    int w    = threadIdx.x >> 6;
    int wid  = blockIdx.x * 4 + w;                // 0..2047
    int row0 = wid * (RF * 16);                   // 64 rows per wave
    int lrow = lane & 15;
    int lq   = lane >> 4;

    // A-fragment build FIRST (its loads are consumed by the f16 converts,
    // so they retire here), then a one-time drain so vmcnt counting of the
    // staging stream is exact.
    f16x8 Fh[RF][2];
#pragma unroll
    for (int rf = 0; rf < RF; rf++)
#pragma unroll
        for (int kc = 0; kc < 2; kc++) {
            const float* zp = z + (size_t)(row0 + rf * 16 + lrow) * ZD + kc * 32 + lq * 8;
            float xv[8];
            *(float4*)(void*)&xv[0] = *(const float4*)(const void*)zp;
            *(float4*)(void*)&xv[4] = *(const float4*)(const void*)(zp + 4);
            f16x8 h;
#pragma unroll
            for (int j = 0; j < 8; j++) h[j] = (_Float16)xv[j];
            Fh[rf][kc] = h;
            // Pin (ONE-TIME): asm defs cannot be rematerialized -> fragments
            // stay register-resident across the loop.
            asm volatile("" : "+v"(Fh[rf][kc]));
        }
    asm volatile("s_waitcnt vmcnt(0)" ::: "memory");  // clean vmcnt baseline

    // Staging prologue: esn (8KB, 2 calls) + pairs 0,1 (stage-ahead=2).
    // Outstanding/wave = 4; iter 0 adds pair2 (=5), its vmcnt(2) retires
    // esn x2 + pair0 before the first barrier.
    {
        const char* esrc = (const char*)ws + 4096 + ((size_t)threadIdx.x << 4);
        __builtin_amdgcn_global_load_lds(
            (const __attribute__((address_space(1))) unsigned int*)esrc,
            (__attribute__((address_space(3))) unsigned int*)((char*)esn_sm + (w << 10)),
            16, 0, 0);
        __builtin_amdgcn_global_load_lds(
            (const __attribute__((address_space(1))) unsigned int*)(esrc + 4096),
            (__attribute__((address_space(3))) unsigned int*)((char*)esn_sm + 4096 + (w << 10)),
            16, 0, 0);
    }
    STAGEP(0, 0);
    STAGEP(1, 1);

    // argmax state on s = dot - esq/2  (argmin d2 == argmax s)
    floatx4 mval[RF], mv2[RF], midx[RF];
#pragma unroll
    for (int rf = 0; rf < RF; rf++)
#pragma unroll
        for (int r = 0; r < 4; r++) {
            mval[rf][r] = -3.0e38f; mv2[rf][r] = -3.0e38f; midx[rf][r] = 0.0f;
        }

    float fcol = (float)lrow;                     // maintained: +16 per tile

    for (int ct = 0; ct < 64; ct += 4) {          // ring slot (CT&3) static
        ITER_R(ct);
        ITER_R(ct + 1);
        ITER_R(ct + 2);
        ITER_R(ct + 3);
    }
    // 2 stages left in flight write dead ring slots; drained by the
    // __syncthreads before the loss reduce.

    float lacc = 0.0f;
#pragma unroll
    for (int rf = 0; rf < RF; rf++)
#pragma unroll
        for (int r = 0; r < 4; r++) {
            float v = mval[rf][r], v2 = mv2[rf][r], fi = midx[rf][r];
            // top-2 max-merge across the 16 lanes of this row (ties: smaller col)
            for (int off = 1; off < 16; off <<= 1) {
                float ov  = __shfl_xor(v,  off, 64);
                float ofi = __shfl_xor(fi, off, 64);
                float ov2 = __shfl_xor(v2, off, 64);
                bool take = (ov > v) || ((ov == v) && (ofi < fi));
                float loser = take ? v : ov;
                v2 = fmaxf(fmaxf(v2, ov2), loser);
                v  = take ? ov  : v;
                fi = take ? ofi : fi;
            }
            int row = row0 + rf * 16 + lq * 4 + r;
            int idx = (int)fi;
            float4 ev = ((const float4*)(const void*)(e + (size_t)idx * ZD))[lrow];
            float4 zv = ((const float4*)(const void*)(z + (size_t)row * ZD))[lrow];
            ((float4*)(void*)(out + (size_t)row * ZD))[lrow] = ev;
            float dx = ev.x - zv.x, dy = ev.y - zv.y;
            float dz = ev.z - zv.z, dw = ev.w - zv.w;
            lacc = fmaf(dx, dx, lacc); lacc = fmaf(dy, dy, lacc);
            lacc = fmaf(dz, dz, lacc); lacc = fmaf(dw, dw, lacc);
            if (lrow == 0) {
                out[(size_t)N_ROWS * ZD + row] = fi;
                if (v - v2 < EPS_S) {
                    unsigned int i = atomicAdd(cntp, 1u);
                    if (i < FLAG_CAP) flags[i] = (unsigned int)row;
                }
            }
        }

    for (int off = 1; off < 64; off <<= 1) lacc += __shfl_xor(lacc, off, 64);
    __shared__ float sm[4];
    if (lane == 0) sm[w] = lacc;
    __syncthreads();
    if (threadIdx.x == 0) atomicAdd(ws, sm[0] + sm[1] + sm[2] + sm[3]);
}

// Exact f64 re-solve, RFIX rows per eT sweep (eT traffic / RFIX).
__global__ __launch_bounds__(256) void vq_fixup(
        const float* __restrict__ z, const float* __restrict__ e,
        float* __restrict__ ws, float* __restrict__ out) {
    const double* esq64 = (const double*)((const char*)ws + 16384);
    const float* eT = (const float*)((const char*)ws + 557056);
    const unsigned int* flags = (const unsigned int*)((const char*)ws + 294912);
    unsigned int cnt = ((const unsigned int*)ws)[1];
    // Overflow fallback: if the flag list overflowed, re-solve EVERY row.
    bool allrows = cnt > FLAG_CAP;
    unsigned int n = allrows ? N_ROWS : cnt;

    // finalize folded in: stream-ordered after vq_mfma, ws[0] is final.
    if (blockIdx.x == 0 && threadIdx.x == 0)
        out[(size_t)N_ROWS * ZD + N_ROWS] = ws[0] * (1.0f / 8388608.0f);
    if (n == 0) return;

    __shared__ float zrow[RFIX][ZD];
    __shared__ int rows_sm[RFIX];
    __shared__ double sd[4][RFIX]; __shared__ int si[4][RFIX];
    __shared__ int sbest[RFIX];
    int t = threadIdx.x, lane = t & 63, w = t >> 6;

    unsigned int ngroups = (n + RFIX - 1) / RFIX;
    for (unsigned int g = blockIdx.x; g < ngroups; g += gridDim.x) {
        __syncthreads();                          // protect LDS from prev iter
        if (t < RFIX) {
            unsigned int u = g * RFIX + (unsigned int)t;
            if (u >= n) u = n - 1;                // pad: duplicate last row
            rows_sm[t] = allrows ? (int)u : (int)flags[u];
        }
        __syncthreads();
        // stage RFIX z rows: 256 threads cover 8 rows x 64 dims in 2 steps
        zrow[t >> 6][t & 63]       = z[(size_t)rows_sm[t >> 6] * ZD + (t & 63)];
        zrow[4 + (t >> 6)][t & 63] = z[(size_t)rows_sm[4 + (t >> 6)] * ZD + (t & 63)];
        __syncthreads();

        double dacc[8][RFIX];
#pragma unroll
        for (int j = 0; j < 8; j++)
#pragma unroll
            for (int r = 0; r < RFIX; r++) dacc[j][r] = 0.0;

        for (int k = 0; k < ZD; k++) {
            const float* ek = eT + k * KCODES + t;
            float e8[8];
#pragma unroll
            for (int j = 0; j < 8; j++) e8[j] = ek[256 * j];
#pragma unroll
            for (int r = 0; r < RFIX; r++) {
                double zk = (double)zrow[r][k];
#pragma unroll
                for (int j = 0; j < 8; j++)
                    dacc[j][r] = fma(zk, (double)e8[j], dacc[j][r]);
            }
        }

        // per-row argmin: thread-local over 8 codes, wave shfl, block merge
#pragma unroll
        for (int r = 0; r < RFIX; r++) {
            double dmin = 1.0e300; int imin = 0;
#pragma unroll
            for (int j = 0; j < 8; j++) {         // ascending c: first wins
                int c = t + 256 * j;
                double d = fma(-2.0, dacc[j][r], esq64[c]);
                if (d < dmin) { dmin = d; imin = c; }
            }
            for (int off = 1; off < 64; off <<= 1) {
                double od = __shfl_xor(dmin, off, 64);
                int    oi = __shfl_xor(imin, off, 64);
                if (od < dmin || (od == dmin && oi < imin)) { dmin = od; imin = oi; }
            }
            if (lane == 0) { sd[w][r] = dmin; si[w][r] = imin; }
        }
        __syncthreads();
        if (t < RFIX) {
            double bd = sd[0][t]; int bi = si[0][t];
            for (int q = 1; q < 4; q++)
                if (sd[q][t] < bd || (sd[q][t] == bd && si[q][t] < bi)) {
                    bd = sd[q][t]; bi = si[q][t];
                }
            sbest[t] = bi;
        }
        __syncthreads();
        // parallel write: t<128 -> row r=t>>4, float4 slot pos=t&15
        if (t < 16 * RFIX) {
            int r = t >> 4, pos = t & 15;
            unsigned int u = g * RFIX + (unsigned int)r;
            if (u < n) {                          // skip padded duplicates
                int row = rows_sm[r]; int bi = sbest[r];
                ((float4*)(void*)(out + (size_t)row * ZD))[pos] =
                    ((const float4*)(const void*)(e + (size_t)bi * ZD))[pos];
                if (pos == 0) out[(size_t)N_ROWS * ZD + row] = (float)bi;
            }
        }
    }
}

extern "C" void kernel_launch(void* const* d_in, const int* in_sizes, int n_in,
                              void* d_out, int out_size, void* d_ws, size_t ws_size,
                              hipStream_t stream) {
    const float* z = (const float*)d_in[0];
    const float* e = (const float*)d_in[1];
    float* out = (float*)d_out;
    float* ws  = (float*)d_ws;

    prep_kernel<<<dim3(512), dim3(256), 0, stream>>>(e, ws);
    vq_mfma<<<dim3(512), dim3(256), 0, stream>>>(z, e, ws, out);
    vq_fixup<<<dim3(1024), dim3(256), 0, stream>>>(z, e, ws, out);
}

// Round 11
// 180.467 us; speedup vs baseline: 1.0637x; 1.0637x over previous
//
#include <hip/hip_runtime.h>

// VQ quantizer, fp32: z [131072,64], e [2048,64].
// d_out (flat f32): z_q [131072*64] | indices [131072] (floats) | loss [1].
//
// R15 (kept): SINGLE-PRODUCT F16 MFMA scan, 131 -> 96us.
// R16 (kept): EPS_S=0.02 (9.1 sigma), fixup RFIX=4 rows/eT-sweep (~25us).
// R17: scan T4 counted-vmcnt ring = NEUTRAL (7th schedule-invariant
//      result -> scan closed at ~91us, structural); RFIX=8 REGRESSED
//      (128 f64 acc VGPRs) -> reverted to 4.
// R18: prep rewritten as LDS-tiled transpose. Old prep wrote
//      eT[lane*2048+c] = 64-way scattered 4B stores (~16x write
//      amplification, latency-bound at 512 blocks) + strided et16 chunks;
//      suspected ~25-40us of the ~65us unattributed block. New prep:
//      32 blocks x 64 codes, coalesced loads -> LDS [64][65] -> fully
//      coalesced eT rows (256B/k), et16 16B-consecutive chunks, per-code
//      f64 esq. Scan byte-identical to R17; fixup = R16's RFIX=4.

#define N_ROWS 131072
#define ZD 64
#define KCODES 2048
#define RF 4                 // 16-row fragments per wave (64 rows/wave)
#define EPS_S 0.02f          // 9.1 sigma of f16 scan pairwise error
#define FLAG_CAP 65536
#define RFIX 4               // rows per eT sweep in fixup

using f16x8   = __attribute__((ext_vector_type(8))) _Float16;
using floatx4 = __attribute__((ext_vector_type(4))) float;

// ws byte layout:
//       0: loss f32 | 4: flag count u32
//    4096: esn f32[2048]   (= -esq/2, summed in f64)
//   16384: esq64 f64[2048]
//   32768: et16, 128 tiles x 2048B; tile = [kb 0..7][code 0..15][8 k] f16
//          (kb = dim>>3, j = dim&7)   ends 294912
//  294912: flags u32[65536]   (ends 557056)
//  557056: eT f32[64*2048]    (ends 1081344)

// LDS-tiled transpose prep: 32 blocks x 256 threads, 64 codes per block.
__global__ __launch_bounds__(256) void prep_kernel(
        const float* __restrict__ e, float* __restrict__ ws) {
    __shared__ float tile[64][65];                // 16.25 KB, pad kills conflicts
    int t = threadIdx.x;
    int c0 = blockIdx.x * 64;
    if (blockIdx.x == 0 && t == 0) { ws[0] = 0.0f; ((unsigned int*)ws)[1] = 0u; }

    float* esn = ws + 1024;
    double* esq64 = (double*)((char*)ws + 16384);
    unsigned short* et = (unsigned short*)((char*)ws + 32768);
    float* eT = (float*)((char*)ws + 557056);

    // Coalesced load: 64 codes x 64 dims; each iter reads 1KB contiguous.
#pragma unroll
    for (int i = 0; i < 16; i++) {
        int idx = i * 256 + t;                    // 0..4095
        int cc = idx >> 6, k = idx & 63;
        tile[cc][k] = e[(size_t)(c0 + cc) * ZD + k];
    }
    __syncthreads();

    // Per-code esq (f64) - threads 0..63, row-read (bank-spread via pad).
    if (t < 64) {
        double s = 0.0;
#pragma unroll
        for (int k = 0; k < 64; k++) { double v = (double)tile[t][k]; s = fma(v, v, s); }
        esq64[c0 + t] = s;
        esn[c0 + t] = (float)(-0.5 * s);
    }

    // eT[k][c0..c0+63]: consecutive t -> consecutive code -> 256B/k rows.
#pragma unroll
    for (int i = 0; i < 16; i++) {
        int idx = i * 256 + t;
        int k = idx >> 6, cc = idx & 63;
        eT[(size_t)k * KCODES + c0 + cc] = tile[cc][k];
    }

    // et16: 4 tiles x 1024 u16 = 512 16B-chunks; consecutive chunk ->
    // consecutive 16B address -> fully coalesced.
#pragma unroll
    for (int i = 0; i < 2; i++) {
        int h = i * 256 + t;                      // chunk 0..511
        int tl   = h >> 7;                        // tile in block 0..3
        int kb   = (h >> 4) & 7;
        int code = h & 15;
        int row  = tl * 16 + code;
        union { _Float16 hf[8]; unsigned int u32[4]; } pk;
#pragma unroll
        for (int j = 0; j < 8; j++) pk.hf[j] = (_Float16)tile[row][kb * 8 + j];
        int gtile = (c0 >> 4) + tl;
        unsigned int* dst = (unsigned int*)(et + (size_t)gtile * 1024 + kb * 128 + code * 8);
        *(uint4*)(void*)dst = *(uint4*)(void*)pk.u32;
    }
}

// 8 MFMAs + argmax update for one 16-code tile (single f16 product).
// Top-2 invariant mval >= mv2: new mv2 = median(s, mval_old, mv2).
#define COMPUTE(H0, H1, EN, FCOL) do {                                       \
    floatx4 _ai = {EN, EN, EN, EN};                                          \
    _Pragma("unroll")                                                        \
    for (int _rf = 0; _rf < RF; _rf++) {                                     \
        floatx4 acc;                                                         \
        acc = __builtin_amdgcn_mfma_f32_16x16x32_f16(Fh[_rf][0], H0, _ai, 0, 0, 0); \
        acc = __builtin_amdgcn_mfma_f32_16x16x32_f16(Fh[_rf][1], H1, acc, 0, 0, 0); \
        _Pragma("unroll")                                                    \
        for (int _r = 0; _r < 4; _r++) {                                     \
            float _s  = acc[_r];                                             \
            bool  _gt = _s > mval[_rf][_r];                                  \
            mv2[_rf][_r]  = __builtin_amdgcn_fmed3f(_s, mval[_rf][_r], mv2[_rf][_r]); \
            midx[_rf][_r] = _gt ? (FCOL) : midx[_rf][_r];                    \
            mval[_rf][_r] = fmaxf(_s, mval[_rf][_r]);                        \
        }                                                                    \
    }                                                                        \
} while (0)

// Stage one 4KB PAIR of tiles (2x 2KB) into ring slot BUF: 256 thr x 16B,
// lane*16-linear (ONE global_load_lds per thread -> exact vmcnt counting).
#define STAGEP(BUF, P) do {                                                  \
    const char* _src = etiles + ((size_t)((P) & 63) << 12)                   \
                       + ((size_t)threadIdx.x << 4);                         \
    __builtin_amdgcn_global_load_lds(                                        \
        (const __attribute__((address_space(1))) unsigned int*)_src,         \
        (__attribute__((address_space(3))) unsigned int*)&tilebuf[BUF][w << 10], \
        16, 0, 0);                                                           \
} while (0)

// T4 ring iteration over a tile PAIR (CT = pair idx 0..63, slot = CT&3):
// stage pair CT+2, counted vmcnt (own pair-CT quarter retired; CT+1,CT+2
// stay in flight), raw barrier, then ds_read + compute.
#define ITER_R(CT) do {                                                      \
    STAGEP(((CT) + 2) & 3, (CT) + 2);                                        \
    asm volatile("s_waitcnt vmcnt(2)" ::: "memory");                         \
    __builtin_amdgcn_s_barrier();                                            \
    float _en0 = esn_sm[(CT) * 32 + lrow];                                   \
    float _en1 = esn_sm[(CT) * 32 + 16 + lrow];                              \
    const char* _tb = tilebuf[(CT) & 3];                                     \
    f16x8 h0, h1;                                                            \
    h0 = *(const f16x8*)(const void*)(_tb + (lane << 4));                    \
    h1 = *(const f16x8*)(const void*)(_tb + 1024 + (lane << 4));             \
    COMPUTE(h0, h1, _en0, fcol);                                             \
    fcol += 16.0f;                                                           \
    h0 = *(const f16x8*)(const void*)(_tb + 2048 + (lane << 4));             \
    h1 = *(const f16x8*)(const void*)(_tb + 3072 + (lane << 4));             \
    COMPUTE(h0, h1, _en1, fcol);                                             \
    fcol += 16.0f;                                                           \
} while (0)

__global__ __launch_bounds__(256, 2) void vq_mfma(
        const float* __restrict__ z, const float* __restrict__ e,
        float* __restrict__ ws, float* __restrict__ out) {
    const char* etiles = (const char*)ws + 32768;
    unsigned int* cntp  = (unsigned int*)ws + 1;
    unsigned int* flags = (unsigned int*)((char*)ws + 294912);

    __shared__ __attribute__((aligned(16))) char tilebuf[4][4096];
    __shared__ __attribute__((aligned(16))) float esn_sm[KCODES];

    int lane = threadIdx.x & 63;
    int w    = threadIdx.x >> 6;
    int wid  = blockIdx.x * 4 + w;                // 0..2047
    int row0 = wid * (RF * 16);                   // 64 rows per wave
    int lrow = lane & 15;
    int lq   = lane >> 4;

    // A-fragment build FIRST (loads retire into the f16 converts), then a
    // one-time drain so vmcnt counting of the staging stream is exact.
    f16x8 Fh[RF][2];
#pragma unroll
    for (int rf = 0; rf < RF; rf++)
#pragma unroll
        for (int kc = 0; kc < 2; kc++) {
            const float* zp = z + (size_t)(row0 + rf * 16 + lrow) * ZD + kc * 32 + lq * 8;
            float xv[8];
            *(float4*)(void*)&xv[0] = *(const float4*)(const void*)zp;
            *(float4*)(void*)&xv[4] = *(const float4*)(const void*)(zp + 4);
            f16x8 h;
#pragma unroll
            for (int j = 0; j < 8; j++) h[j] = (_Float16)xv[j];
            Fh[rf][kc] = h;
            // Pin (ONE-TIME): asm defs cannot be rematerialized.
            asm volatile("" : "+v"(Fh[rf][kc]));
        }
    asm volatile("s_waitcnt vmcnt(0)" ::: "memory");  // clean vmcnt baseline

    // Staging prologue: esn (8KB, 2 calls) + pairs 0,1 (stage-ahead=2).
    {
        const char* esrc = (const char*)ws + 4096 + ((size_t)threadIdx.x << 4);
        __builtin_amdgcn_global_load_lds(
            (const __attribute__((address_space(1))) unsigned int*)esrc,
            (__attribute__((address_space(3))) unsigned int*)((char*)esn_sm + (w << 10)),
            16, 0, 0);
        __builtin_amdgcn_global_load_lds(
            (const __attribute__((address_space(1))) unsigned int*)(esrc + 4096),
            (__attribute__((address_space(3))) unsigned int*)((char*)esn_sm + 4096 + (w << 10)),
            16, 0, 0);
    }
    STAGEP(0, 0);
    STAGEP(1, 1);

    // argmax state on s = dot - esq/2  (argmin d2 == argmax s)
    floatx4 mval[RF], mv2[RF], midx[RF];
#pragma unroll
    for (int rf = 0; rf < RF; rf++)
#pragma unroll
        for (int r = 0; r < 4; r++) {
            mval[rf][r] = -3.0e38f; mv2[rf][r] = -3.0e38f; midx[rf][r] = 0.0f;
        }

    float fcol = (float)lrow;                     // maintained: +16 per tile

    for (int ct = 0; ct < 64; ct += 4) {          // ring slot (CT&3) static
        ITER_R(ct);
        ITER_R(ct + 1);
        ITER_R(ct + 2);
        ITER_R(ct + 3);
    }
    // 2 stages left in flight write dead ring slots; drained by the
    // __syncthreads before the loss reduce.

    float lacc = 0.0f;
#pragma unroll
    for (int rf = 0; rf < RF; rf++)
#pragma unroll
        for (int r = 0; r < 4; r++) {
            float v = mval[rf][r], v2 = mv2[rf][r], fi = midx[rf][r];
            // top-2 max-merge across the 16 lanes of this row (ties: smaller col)
            for (int off = 1; off < 16; off <<= 1) {
                float ov  = __shfl_xor(v,  off, 64);
                float ofi = __shfl_xor(fi, off, 64);
                float ov2 = __shfl_xor(v2, off, 64);
                bool take = (ov > v) || ((ov == v) && (ofi < fi));
                float loser = take ? v : ov;
                v2 = fmaxf(fmaxf(v2, ov2), loser);
                v  = take ? ov  : v;
                fi = take ? ofi : fi;
            }
            int row = row0 + rf * 16 + lq * 4 + r;
            int idx = (int)fi;
            float4 ev = ((const float4*)(const void*)(e + (size_t)idx * ZD))[lrow];
            float4 zv = ((const float4*)(const void*)(z + (size_t)row * ZD))[lrow];
            ((float4*)(void*)(out + (size_t)row * ZD))[lrow] = ev;
            float dx = ev.x - zv.x, dy = ev.y - zv.y;
            float dz = ev.z - zv.z, dw = ev.w - zv.w;
            lacc = fmaf(dx, dx, lacc); lacc = fmaf(dy, dy, lacc);
            lacc = fmaf(dz, dz, lacc); lacc = fmaf(dw, dw, lacc);
            if (lrow == 0) {
                out[(size_t)N_ROWS * ZD + row] = fi;
                if (v - v2 < EPS_S) {
                    unsigned int i = atomicAdd(cntp, 1u);
                    if (i < FLAG_CAP) flags[i] = (unsigned int)row;
                }
            }
        }

    for (int off = 1; off < 64; off <<= 1) lacc += __shfl_xor(lacc, off, 64);
    __shared__ float sm[4];
    if (lane == 0) sm[w] = lacc;
    __syncthreads();
    if (threadIdx.x == 0) atomicAdd(ws, sm[0] + sm[1] + sm[2] + sm[3]);
}

// Exact f64 re-solve, RFIX=4 rows per eT sweep (R16's measured-best form).
__global__ __launch_bounds__(256) void vq_fixup(
        const float* __restrict__ z, const float* __restrict__ e,
        float* __restrict__ ws, float* __restrict__ out) {
    const double* esq64 = (const double*)((const char*)ws + 16384);
    const float* eT = (const float*)((const char*)ws + 557056);
    const unsigned int* flags = (const unsigned int*)((const char*)ws + 294912);
    unsigned int cnt = ((const unsigned int*)ws)[1];
    // Overflow fallback: if the flag list overflowed, re-solve EVERY row.
    bool allrows = cnt > FLAG_CAP;
    unsigned int n = allrows ? N_ROWS : cnt;

    // finalize folded in: stream-ordered after vq_mfma, ws[0] is final.
    if (blockIdx.x == 0 && threadIdx.x == 0)
        out[(size_t)N_ROWS * ZD + N_ROWS] = ws[0] * (1.0f / 8388608.0f);
    if (n == 0) return;

    __shared__ float zrow[RFIX][ZD];
    __shared__ int rows_sm[RFIX];
    __shared__ double sd[4][RFIX]; __shared__ int si[4][RFIX];
    __shared__ int sbest[RFIX];
    int t = threadIdx.x, lane = t & 63, w = t >> 6;

    unsigned int ngroups = (n + RFIX - 1) / RFIX;
    for (unsigned int g = blockIdx.x; g < ngroups; g += gridDim.x) {
        __syncthreads();                          // protect LDS from prev iter
        if (t < RFIX) {
            unsigned int u = g * RFIX + (unsigned int)t;
            if (u >= n) u = n - 1;                // pad: duplicate last row
            rows_sm[t] = allrows ? (int)u : (int)flags[u];
        }
        __syncthreads();
        // stage RFIX z rows: 256 threads cover 4 rows x 64 dims
        zrow[t >> 6][t & 63] = z[(size_t)rows_sm[t >> 6] * ZD + (t & 63)];
        __syncthreads();

        double dacc[8][RFIX];
#pragma unroll
        for (int j = 0; j < 8; j++)
#pragma unroll
            for (int r = 0; r < RFIX; r++) dacc[j][r] = 0.0;

        for (int k = 0; k < ZD; k++) {
            const float* ek = eT + k * KCODES + t;
            float e8[8];
#pragma unroll
            for (int j = 0; j < 8; j++) e8[j] = ek[256 * j];
#pragma unroll
            for (int r = 0; r < RFIX; r++) {
                double zk = (double)zrow[r][k];
#pragma unroll
                for (int j = 0; j < 8; j++)
                    dacc[j][r] = fma(zk, (double)e8[j], dacc[j][r]);
            }
        }

        // per-row argmin: thread-local over 8 codes, wave shfl, block merge
#pragma unroll
        for (int r = 0; r < RFIX; r++) {
            double dmin = 1.0e300; int imin = 0;
#pragma unroll
            for (int j = 0; j < 8; j++) {         // ascending c: first wins
                int c = t + 256 * j;
                double d = fma(-2.0, dacc[j][r], esq64[c]);
                if (d < dmin) { dmin = d; imin = c; }
            }
            for (int off = 1; off < 64; off <<= 1) {
                double od = __shfl_xor(dmin, off, 64);
                int    oi = __shfl_xor(imin, off, 64);
                if (od < dmin || (od == dmin && oi < imin)) { dmin = od; imin = oi; }
            }
            if (lane == 0) { sd[w][r] = dmin; si[w][r] = imin; }
        }
        __syncthreads();
        if (t < RFIX) {
            double bd = sd[0][t]; int bi = si[0][t];
            for (int q = 1; q < 4; q++)
                if (sd[q][t] < bd || (sd[q][t] == bd && si[q][t] < bi)) {
                    bd = sd[q][t]; bi = si[q][t];
                }
            sbest[t] = bi;
        }
        __syncthreads();
        // parallel write: t<64 -> row r=t>>4, float4 slot pos=t&15
        if (t < 16 * RFIX) {
            int r = t >> 4, pos = t & 15;
            unsigned int u = g * RFIX + (unsigned int)r;
            if (u < n) {                          // skip padded duplicates
                int row = rows_sm[r]; int bi = sbest[r];
                ((float4*)(void*)(out + (size_t)row * ZD))[pos] =
                    ((const float4*)(const void*)(e + (size_t)bi * ZD))[pos];
                if (pos == 0) out[(size_t)N_ROWS * ZD + row] = (float)bi;
            }
        }
    }
}

extern "C" void kernel_launch(void* const* d_in, const int* in_sizes, int n_in,
                              void* d_out, int out_size, void* d_ws, size_t ws_size,
                              hipStream_t stream) {
    const float* z = (const float*)d_in[0];
    const float* e = (const float*)d_in[1];
    float* out = (float*)d_out;
    float* ws  = (float*)d_ws;

    prep_kernel<<<dim3(32), dim3(256), 0, stream>>>(e, ws);
    vq_mfma<<<dim3(512), dim3(256), 0, stream>>>(z, e, ws, out);
    vq_fixup<<<dim3(1024), dim3(256), 0, stream>>>(z, e, ws, out);
}